// Round 7
// baseline (161.260 us; speedup 1.0000x reference)
//
#include <hip/hip_runtime.h>

typedef unsigned short u16;
typedef unsigned int u32;
typedef __attribute__((ext_vector_type(4))) float f32x4;
typedef __attribute__((ext_vector_type(8))) short bf16x8;
typedef __attribute__((ext_vector_type(8))) unsigned short u16x8;

#define SEQ   2048
#define NB    2
#define NH    8
#define HD    128
#define EMB   1024
#define WIN   128
#define MTOT  4096      // NB*SEQ
#define NQKV  3072
#define HSZ   (SEQ*HD)          // elements per (b,h) plane
#define QKVSZ (NB*NH*HSZ)       // elements per q/k/v tensor

static __device__ __forceinline__ u16 f2bf(float f){
  u32 x = __builtin_bit_cast(u32, f);
  x += 0x7fffu + ((x >> 16) & 1u);          // round-to-nearest-even
  return (u16)(x >> 16);
}

static __device__ __forceinline__ void gload_lds16(const void* g, void* l){
  __builtin_amdgcn_global_load_lds((__attribute__((address_space(1))) void*)(void*)(g),
                                   (__attribute__((address_space(3))) void*)(l), 16, 0, 0);
}

// ---------------- fused prep: x->bf16, Wqkv^T->bf16, Wproj^T->bf16 ----------

__global__ __launch_bounds__(256) void prep(
    const float* __restrict__ x, const float* __restrict__ Wqkv,
    const float* __restrict__ Wproj,
    u16* __restrict__ Xb, u16* __restrict__ Wqt, u16* __restrict__ Wpt)
{
  __shared__ float tile[32][33];
  const int b = blockIdx.x, tid = threadIdx.x;
  if (b < 2048){
    const int i = (b * 256 + tid) * 8;
    float4 a = *(const float4*)(x + i);
    float4 c = *(const float4*)(x + i + 4);
    uint4 o;
    o.x = (u32)f2bf(a.x) | ((u32)f2bf(a.y) << 16);
    o.y = (u32)f2bf(a.z) | ((u32)f2bf(a.w) << 16);
    o.z = (u32)f2bf(c.x) | ((u32)f2bf(c.y) << 16);
    o.w = (u32)f2bf(c.z) | ((u32)f2bf(c.w) << 16);
    *(uint4*)(Xb + i) = o;
    return;
  }
  const float* in; u16* out; int R, C, bxi, byi;
  if (b < 5120){
    const int bb = b - 2048;
    in = Wqkv; out = Wqt; R = EMB; C = NQKV;
    bxi = bb % 96; byi = bb / 96;
  } else {
    const int bb = b - 5120;
    in = Wproj; out = Wpt; R = EMB; C = EMB;
    bxi = bb & 31; byi = bb >> 5;
  }
  const int bx = bxi * 32, by = byi * 32;
  const int tx = tid & 31, ty = tid >> 5;   // 32 x 8
  #pragma unroll
  for (int i = 0; i < 32; i += 8)
    tile[ty + i][tx] = in[(size_t)(by + ty + i) * C + bx + tx];
  __syncthreads();
  #pragma unroll
  for (int i = 0; i < 32; i += 8)
    out[(size_t)(bx + ty + i) * R + by + tx] = f2bf(tile[tx][ty + i]);
}

// ---------------- QKV GEMM: 128x128 tile, LDS-transpose vectorized epilogue --
// (R4-proven epilogue structure, pitch 136 for 16B alignment; NO XCD swizzle)

__global__ __launch_bounds__(256) void gemm_qkv(
    const u16* __restrict__ A,    // [4096][1024] bf16
    const u16* __restrict__ Bt,   // [3072][1024] bf16
    const float* __restrict__ bias,
    u16* __restrict__ obf)        // qkv base
{
  constexpr int K = 1024, BK = 64;
  __shared__ char smem[34816];             // As(16K)+Bs(16K) / Ct[128][136] bf16
  u16* As = (u16*)smem;
  u16* Bs = (u16*)(smem + 16384);
  u16* Ct = (u16*)smem;

  const int tid = threadIdx.x, lane = tid & 63, wave = tid >> 6;
  const int m0 = blockIdx.y * 128, n0 = blockIdx.x * 128;
  const int wr = (wave >> 1) * 64, wc = (wave & 1) * 64;
  const int fr = lane & 15, hk = lane >> 4;

  const int srow = lane >> 3;                                   // 0..7
  const int scol = ((((lane & 7) << 4) ^ (srow << 4)) >> 1);    // pre-swizzled src col
  const u16* ag = A  + (size_t)(m0 + wave * 32 + srow) * K + scol;
  const u16* bg = Bt + (size_t)(n0 + wave * 32 + srow) * K + scol;
  u16* al = &As[wave * 32 * 64];
  u16* bl = &Bs[wave * 32 * 64];

  f32x4 acc[4][4] = {};

  for (int kt = 0; kt < K / BK; ++kt){
    #pragma unroll
    for (int j = 0; j < 4; ++j){
      gload_lds16(ag + (size_t)j * 8 * K + kt * BK, al + j * 8 * 64);
      gload_lds16(bg + (size_t)j * 8 * K + kt * BK, bl + j * 8 * 64);
    }
    __syncthreads();
    #pragma unroll
    for (int ks = 0; ks < 2; ++ks){
      const int colb = ((ks << 6) + (hk << 4)) ^ ((lane & 7) << 4);
      bf16x8 af[4], bfr[4];
      #pragma unroll
      for (int mi = 0; mi < 4; ++mi)
        af[mi] = *(const bf16x8*)((const char*)As + (wr + mi * 16 + fr) * 128 + colb);
      #pragma unroll
      for (int ni = 0; ni < 4; ++ni)
        bfr[ni] = *(const bf16x8*)((const char*)Bs + (wc + ni * 16 + fr) * 128 + colb);
      #pragma unroll
      for (int mi = 0; mi < 4; ++mi)
        #pragma unroll
        for (int ni = 0; ni < 4; ++ni)
          acc[mi][ni] = __builtin_amdgcn_mfma_f32_16x16x32_bf16(af[mi], bfr[ni], acc[mi][ni], 0, 0, 0);
    }
    __syncthreads();
  }

  // epilogue: acc -> LDS bf16 tile [128][136-pitch], then vectorized scatter
  #pragma unroll
  for (int mi = 0; mi < 4; ++mi){
    const int r = wr + mi * 16 + (hk << 2);
    #pragma unroll
    for (int ni = 0; ni < 4; ++ni){
      const int c = wc + ni * 16 + fr;
      const float bs = bias[n0 + c];
      #pragma unroll
      for (int j = 0; j < 4; ++j)
        Ct[(r + j) * 136 + c] = f2bf(acc[mi][ni][j] + bs);
    }
  }
  __syncthreads();
  #pragma unroll
  for (int it = 0; it < 8; ++it){
    const int flat = it * 256 + tid;
    const int row = flat >> 4, col8 = (flat & 15) * 8;
    u16x8 v = *(const u16x8*)(Ct + row * 136 + col8);
    const int rg = m0 + row, cg = n0 + col8;
    const int b_ = rg >> 11, t = rg & 2047;
    const int which = cg >> 10, hm = cg & 1023;
    *(u16x8*)(obf + (size_t)which * QKVSZ
                  + ((size_t)(b_ * NH + (hm >> 7)) * SEQ + t) * HD + (hm & 127)) = v;
  }
}

// ---------------- proj GEMM: 128x64 tile, LDS-transpose float4 epilogue ------

__global__ __launch_bounds__(256) void gemm_proj(
    const u16* __restrict__ A,    // [4096][1024] bf16
    const u16* __restrict__ Bt,   // [1024][1024] bf16
    const float* __restrict__ bias,
    float* __restrict__ of)
{
  constexpr int K = 1024, BK = 64;
  __shared__ char smem[128 * 72 * 4];      // As(16K)+Bs(8K) / Ct[128][72] f32
  u16* As = (u16*)smem;
  u16* Bs = (u16*)(smem + 16384);
  float* Ct = (float*)smem;

  const int tid = threadIdx.x, lane = tid & 63, wave = tid >> 6;
  const int m0 = blockIdx.y * 128, n0 = blockIdx.x * 64;
  const int wr = (wave >> 1) * 64, wc = (wave & 1) * 32;
  const int fr = lane & 15, hk = lane >> 4;

  const int prow = tid >> 3;                 // 0..31
  const int sw8 = (tid & 7) ^ (prow & 7);
  const u16* ag = A  + (size_t)(m0 + prow) * K + sw8 * 8;
  const u16* bg = Bt + (size_t)(n0 + prow) * K + sw8 * 8;

  f32x4 acc[4][2] = {};

  for (int kt = 0; kt < K / BK; ++kt){
    #pragma unroll
    for (int r = 0; r < 4; ++r)
      gload_lds16(ag + (size_t)(r * 32) * K + kt * BK, (char*)As + r * 4096 + tid * 16);
    #pragma unroll
    for (int r = 0; r < 2; ++r)
      gload_lds16(bg + (size_t)(r * 32) * K + kt * BK, (char*)Bs + r * 4096 + tid * 16);
    __syncthreads();
    #pragma unroll
    for (int ks = 0; ks < 2; ++ks){
      bf16x8 af[4], bfr[2];
      #pragma unroll
      for (int mi = 0; mi < 4; ++mi){
        const int r = wr + mi * 16 + fr;
        const int cb = ((ks << 6) + (hk << 4)) ^ ((r & 7) << 4);
        af[mi] = *(const bf16x8*)((const char*)As + r * 128 + cb);
      }
      #pragma unroll
      for (int ni = 0; ni < 2; ++ni){
        const int r = wc + ni * 16 + fr;
        const int cb = ((ks << 6) + (hk << 4)) ^ ((r & 7) << 4);
        bfr[ni] = *(const bf16x8*)((const char*)Bs + r * 128 + cb);
      }
      #pragma unroll
      for (int mi = 0; mi < 4; ++mi)
        #pragma unroll
        for (int ni = 0; ni < 2; ++ni)
          acc[mi][ni] = __builtin_amdgcn_mfma_f32_16x16x32_bf16(af[mi], bfr[ni], acc[mi][ni], 0, 0, 0);
    }
    __syncthreads();
  }

  #pragma unroll
  for (int mi = 0; mi < 4; ++mi){
    const int r = wr + mi * 16 + (hk << 2);
    #pragma unroll
    for (int ni = 0; ni < 2; ++ni){
      const int c = wc + ni * 16 + fr;
      const float bs = bias[n0 + c];
      #pragma unroll
      for (int j = 0; j < 4; ++j)
        Ct[(r + j) * 72 + c] = acc[mi][ni][j] + bs;
    }
  }
  __syncthreads();
  #pragma unroll
  for (int it = 0; it < 8; ++it){
    const int flat = it * 256 + tid;
    const int row = flat >> 4, col4 = (flat & 15) * 4;
    float4 v = *(const float4*)(Ct + row * 72 + col4);
    *(float4*)(of + (size_t)(m0 + row) * EMB + n0 + col4) = v;
  }
}

// ---------------- sliding-window attention (R6 sync structure) ---------------
// Change vs R6: softmax normalizes in registers and writes P ONCE as bf16
// (into S's storage, after a barrier that ends all f32 S reads); PV reads one
// ds_read_b128 P-fragment instead of 2x float4 + 8x f2bf.

__global__ __launch_bounds__(256) void attn_kernel(
    const u16* __restrict__ QKVb, const float* __restrict__ gate, u16* __restrict__ Ao)
{
  __shared__ float S[64 * 196];     // f32 scores; later re-used as bf16 P [64][200]
  __shared__ u16 KV[128 * 72];
  const int tid = threadIdx.x, lane = tid & 63, wave = tid >> 6;
  const int q0 = blockIdx.x * 64;
  const int bh = blockIdx.y;
  const u16* Qg = QKVb + (size_t)bh * HSZ;
  const u16* Kg = QKVb + (size_t)QKVSZ + (size_t)bh * HSZ;
  const u16* Vg = QKVb + (size_t)2 * QKVSZ + (size_t)bh * HSZ;
  const int kstart = q0 - WIN;
  u16* Pbf = (u16*)S;               // bf16 P, pitch 200 (25.6 KB < 50.2 KB)

  bf16x8 qf[4];
  {
    const u16* qp = Qg + (size_t)(q0 + wave * 16 + (lane & 15)) * HD + 8 * (lane >> 4);
    #pragma unroll
    for (int ks = 0; ks < 4; ++ks) qf[ks] = *(const bf16x8*)(qp + ks * 32);
  }
  const float scale = 0.08838834764831845f;

  for (int c = 0; c < 3; ++c){
    if (kstart + c * 64 + 64 <= 0){       // chunk entirely before t=0
      for (int t2 = tid; t2 < 64 * 64; t2 += 256)
        S[(t2 >> 6) * 196 + c * 64 + (t2 & 63)] = -1e30f;
      continue;
    }
    {
      const int keyl = tid >> 2;
      int krow = kstart + c * 64 + keyl;
      krow = min(max(krow, 0), SEQ - 1);
      const u16* kp = Kg + (size_t)krow * HD + (tid & 3) * 8;
      u16* ksh = &KV[keyl * 136 + (tid & 3) * 8];
      #pragma unroll
      for (int r = 0; r < 4; ++r)
        *(uint4*)(ksh + r * 32) = *(const uint4*)(kp + r * 32);
    }
    __syncthreads();
    f32x4 sacc[4] = {};
    #pragma unroll
    for (int ks = 0; ks < 4; ++ks){
      #pragma unroll
      for (int nf = 0; nf < 4; ++nf){
        bf16x8 kf = *(const bf16x8*)(&KV[(nf * 16 + (lane & 15)) * 136 + ks * 32 + 8 * (lane >> 4)]);
        sacc[nf] = __builtin_amdgcn_mfma_f32_16x16x32_bf16(qf[ks], kf, sacc[nf], 0, 0, 0);
      }
    }
    #pragma unroll
    for (int nf = 0; nf < 4; ++nf){
      const int kc = c * 64 + nf * 16 + (lane & 15);
      const int kg = kstart + kc;
      #pragma unroll
      for (int j = 0; j < 4; ++j){
        const int qr = wave * 16 + ((lane >> 4) << 2) + j;
        const int qg = q0 + qr;
        const bool ok = (kg >= 0) && (kg <= qg) && (qg - kg <= WIN);
        S[qr * 196 + kc] = ok ? sacc[nf][j] * scale : -1e30f;
      }
    }
    __syncthreads();
  }

  { // softmax: 4 lanes per row; normalize in regs, write bf16 P once
    const int r = tid >> 2, sub = tid & 3;
    float4 v[12];
    float mx = -1e30f;
    #pragma unroll
    for (int i = 0; i < 12; ++i){
      v[i] = *(const float4*)(&S[r * 196 + (sub + 4 * i) * 4]);
      mx = fmaxf(mx, fmaxf(fmaxf(v[i].x, v[i].y), fmaxf(v[i].z, v[i].w)));
    }
    mx = fmaxf(mx, __shfl_xor(mx, 1));
    mx = fmaxf(mx, __shfl_xor(mx, 2));
    float sum = 0.f;
    #pragma unroll
    for (int i = 0; i < 12; ++i){
      v[i].x = __expf(v[i].x - mx); v[i].y = __expf(v[i].y - mx);
      v[i].z = __expf(v[i].z - mx); v[i].w = __expf(v[i].w - mx);
      sum += v[i].x + v[i].y + v[i].z + v[i].w;
    }
    sum += __shfl_xor(sum, 1);
    sum += __shfl_xor(sum, 2);
    const float inv = 1.0f / sum;
    __syncthreads();               // ALL f32 S reads complete before bf16 overwrite
    #pragma unroll
    for (int i = 0; i < 12; ++i){
      uint2 w;
      w.x = (u32)f2bf(v[i].x * inv) | ((u32)f2bf(v[i].y * inv) << 16);
      w.y = (u32)f2bf(v[i].z * inv) | ((u32)f2bf(v[i].w * inv) << 16);
      *(uint2*)(Pbf + r * 200 + (sub + 4 * i) * 4) = w;
    }
  }
  __syncthreads();   // P visible to all waves

  f32x4 oacc[8] = {};
  for (int c = 0; c < 3; ++c){
    if (kstart + c * 64 + 64 <= 0) continue;
    {
      const int keyl = tid & 63;
      int krow = kstart + c * 64 + keyl;
      krow = min(max(krow, 0), SEQ - 1);
      const u16* vp = Vg + (size_t)krow * HD + (tid >> 6) * 32;
      #pragma unroll
      for (int r2 = 0; r2 < 4; ++r2){
        u16x8 vv = *(const u16x8*)(vp + r2 * 8);
        const int dbase = (tid >> 6) * 32 + r2 * 8;
        #pragma unroll
        for (int j = 0; j < 8; ++j)
          KV[(dbase + j) * 72 + keyl] = vv[j];
      }
    }
    __syncthreads();
    #pragma unroll
    for (int ks = 0; ks < 2; ++ks){
      bf16x8 pf = *(const bf16x8*)(Pbf + (wave * 16 + (lane & 15)) * 200
                                        + c * 64 + ks * 32 + 8 * (lane >> 4));
      #pragma unroll
      for (int nf = 0; nf < 8; ++nf){
        bf16x8 vf = *(const bf16x8*)(&KV[(nf * 16 + (lane & 15)) * 72 + ks * 32 + 8 * (lane >> 4)]);
        oacc[nf] = __builtin_amdgcn_mfma_f32_16x16x32_bf16(pf, vf, oacc[nf], 0, 0, 0);
      }
    }
    __syncthreads();
  }

  // epilogue: oacc*gate -> LDS bf16 [64][132-pitch] (reuse S), then u16x8 stores
  {
    u16* T2 = (u16*)S;
    const int b = bh >> 3, h = bh & 7;
    const int fr_ = lane & 15, hk_ = lane >> 4;
    #pragma unroll
    for (int nf = 0; nf < 8; ++nf){
      const int d = nf * 16 + fr_;
      const float gv = gate[h * HD + d];
      #pragma unroll
      for (int j = 0; j < 4; ++j){
        const int qr = wave * 16 + (hk_ << 2) + j;
        T2[qr * 132 + d] = f2bf(oacc[nf][j] * gv);
      }
    }
    __syncthreads();
    #pragma unroll
    for (int it = 0; it < 4; ++it){
      const int flat = it * 256 + tid;
      const int row = flat >> 4, col8 = (flat & 15) * 8;
      u16x8 v = *(const u16x8*)(T2 + row * 132 + col8);
      *(u16x8*)(Ao + ((size_t)(b * SEQ + q0 + row)) * EMB + h * HD + col8) = v;
    }
  }
}

// ---------------- launch ----------------

extern "C" void kernel_launch(void* const* d_in, const int* in_sizes, int n_in,
                              void* d_out, int out_size, void* d_ws, size_t ws_size,
                              hipStream_t stream)
{
  const float* x     = (const float*)d_in[0];
  const float* Wqkv  = (const float*)d_in[1];
  const float* bqkv  = (const float*)d_in[2];
  const float* Wproj = (const float*)d_in[3];
  const float* bproj = (const float*)d_in[4];
  const float* gate  = (const float*)d_in[5];
  float* out = (float*)d_out;

  u16* Xb   = (u16*)d_ws;                        // [4096][1024]
  u16* Wqt  = Xb   + (size_t)MTOT * EMB;         // [3072][1024]
  u16* Wpt  = Wqt  + (size_t)NQKV * EMB;         // [1024][1024]
  u16* QKVb = Wpt  + (size_t)EMB * EMB;          // q,k,v: [B,H,T,D]
  u16* Ao   = QKVb + (size_t)3 * QKVSZ;          // [4096][1024] gated attn out

  prep<<<dim3(6144), dim3(256), 0, stream>>>(x, Wqkv, Wproj, Xb, Wqt, Wpt);

  gemm_qkv<<<dim3(NQKV / 128, MTOT / 128), dim3(256), 0, stream>>>(Xb, Wqt, bqkv, QKVb);

  attn_kernel<<<dim3(SEQ / 64, NB * NH), dim3(256), 0, stream>>>(QKVb, gate, Ao);

  gemm_proj<<<dim3(EMB / 64, MTOT / 128), dim3(256), 0, stream>>>(Ao, Wpt, bproj, out);
}

// Round 8
// 149.006 us; speedup vs baseline: 1.0822x; 1.0822x over previous
//
#include <hip/hip_runtime.h>

typedef unsigned short u16;
typedef unsigned int u32;
typedef __attribute__((ext_vector_type(4))) float f32x4;
typedef __attribute__((ext_vector_type(8))) short bf16x8;
typedef __attribute__((ext_vector_type(8))) unsigned short u16x8;

#define SEQ   2048
#define NB    2
#define NH    8
#define HD    128
#define EMB   1024
#define WIN   128
#define MTOT  4096      // NB*SEQ
#define NQKV  3072
#define HSZ   (SEQ*HD)          // elements per (b,h) plane
#define QKVSZ (NB*NH*HSZ)       // elements per q/k/v tensor

static __device__ __forceinline__ u16 f2bf(float f){
  u32 x = __builtin_bit_cast(u32, f);
  x += 0x7fffu + ((x >> 16) & 1u);          // round-to-nearest-even
  return (u16)(x >> 16);
}

static __device__ __forceinline__ void gload_lds16(const void* g, void* l){
  __builtin_amdgcn_global_load_lds((__attribute__((address_space(1))) void*)(void*)(g),
                                   (__attribute__((address_space(3))) void*)(l), 16, 0, 0);
}

// ---------------- fused prep: x->bf16, Wqkv^T->bf16, Wproj^T->bf16 ----------

__global__ __launch_bounds__(256) void prep(
    const float* __restrict__ x, const float* __restrict__ Wqkv,
    const float* __restrict__ Wproj,
    u16* __restrict__ Xb, u16* __restrict__ Wqt, u16* __restrict__ Wpt)
{
  __shared__ float tile[32][33];
  const int b = blockIdx.x, tid = threadIdx.x;
  if (b < 2048){
    const int i = (b * 256 + tid) * 8;
    float4 a = *(const float4*)(x + i);
    float4 c = *(const float4*)(x + i + 4);
    uint4 o;
    o.x = (u32)f2bf(a.x) | ((u32)f2bf(a.y) << 16);
    o.y = (u32)f2bf(a.z) | ((u32)f2bf(a.w) << 16);
    o.z = (u32)f2bf(c.x) | ((u32)f2bf(c.y) << 16);
    o.w = (u32)f2bf(c.z) | ((u32)f2bf(c.w) << 16);
    *(uint4*)(Xb + i) = o;
    return;
  }
  const float* in; u16* out; int R, C, bxi, byi;
  if (b < 5120){
    const int bb = b - 2048;
    in = Wqkv; out = Wqt; R = EMB; C = NQKV;
    bxi = bb % 96; byi = bb / 96;
  } else {
    const int bb = b - 5120;
    in = Wproj; out = Wpt; R = EMB; C = EMB;
    bxi = bb & 31; byi = bb >> 5;
  }
  const int bx = bxi * 32, by = byi * 32;
  const int tx = tid & 31, ty = tid >> 5;   // 32 x 8
  #pragma unroll
  for (int i = 0; i < 32; i += 8)
    tile[ty + i][tx] = in[(size_t)(by + ty + i) * C + bx + tx];
  __syncthreads();
  #pragma unroll
  for (int i = 0; i < 32; i += 8)
    out[(size_t)(bx + ty + i) * R + by + tx] = f2bf(tile[tx][ty + i]);
}

// ---------------- QKV GEMM: 128x128 tile, scalar-scatter epilogue (R6-exact) -

__global__ __launch_bounds__(256) void gemm_qkv(
    const u16* __restrict__ A,    // [4096][1024] bf16
    const u16* __restrict__ Bt,   // [3072][1024] bf16
    const float* __restrict__ bias,
    u16* __restrict__ obf)        // qkv base
{
  constexpr int K = 1024, BK = 64;
  __shared__ u16 As[128 * 64];
  __shared__ u16 Bs[128 * 64];
  const int tid = threadIdx.x, lane = tid & 63, wave = tid >> 6;
  const int m0 = blockIdx.y * 128, n0 = blockIdx.x * 128;
  const int wr = (wave >> 1) * 64, wc = (wave & 1) * 64;

  const int srow = lane >> 3;                                   // 0..7
  const int scol = ((((lane & 7) << 4) ^ (srow << 4)) >> 1);    // pre-swizzled src col
  const u16* ag = A  + (size_t)(m0 + wave * 32 + srow) * K + scol;
  const u16* bg = Bt + (size_t)(n0 + wave * 32 + srow) * K + scol;
  u16* al = &As[wave * 32 * 64];
  u16* bl = &Bs[wave * 32 * 64];

  f32x4 acc[4][4] = {};

  for (int kt = 0; kt < K / BK; ++kt){
    #pragma unroll
    for (int j = 0; j < 4; ++j){
      gload_lds16(ag + (size_t)j * 8 * K + kt * BK, al + j * 8 * 64);
      gload_lds16(bg + (size_t)j * 8 * K + kt * BK, bl + j * 8 * 64);
    }
    __syncthreads();
    #pragma unroll
    for (int ks = 0; ks < 2; ++ks){
      const int fr = lane & 15;
      const int colb = ((ks << 6) + ((lane >> 4) << 4)) ^ ((lane & 7) << 4);
      bf16x8 af[4], bfr[4];
      #pragma unroll
      for (int mi = 0; mi < 4; ++mi)
        af[mi] = *(const bf16x8*)((const char*)As + (wr + mi * 16 + fr) * 128 + colb);
      #pragma unroll
      for (int ni = 0; ni < 4; ++ni)
        bfr[ni] = *(const bf16x8*)((const char*)Bs + (wc + ni * 16 + fr) * 128 + colb);
      #pragma unroll
      for (int mi = 0; mi < 4; ++mi)
        #pragma unroll
        for (int ni = 0; ni < 4; ++ni)
          acc[mi][ni] = __builtin_amdgcn_mfma_f32_16x16x32_bf16(af[mi], bfr[ni], acc[mi][ni], 0, 0, 0);
    }
    __syncthreads();
  }

  #pragma unroll
  for (int mi = 0; mi < 4; ++mi){
    const int rg = m0 + wr + mi * 16 + ((lane >> 4) << 2);
    const int b_ = rg >> 11, t = rg & 2047;
    #pragma unroll
    for (int ni = 0; ni < 4; ++ni){
      const int cg = n0 + wc + ni * 16 + (lane & 15);
      const float bs = bias[cg];
      const int which = cg >> 10, hm = cg & 1023;
      u16* dst = obf + (size_t)which * QKVSZ
                     + ((size_t)(b_ * NH + (hm >> 7)) * SEQ + t) * HD + (hm & 127);
      #pragma unroll
      for (int j = 0; j < 4; ++j)
        dst[(size_t)j * HD] = f2bf(acc[mi][ni][j] + bs);
    }
  }
}

// ---------------- proj GEMM: 128x64 tile, LDS-transpose float4 epilogue ------

__global__ __launch_bounds__(256) void gemm_proj(
    const u16* __restrict__ A,    // [4096][1024] bf16
    const u16* __restrict__ Bt,   // [1024][1024] bf16
    const float* __restrict__ bias,
    float* __restrict__ of)
{
  constexpr int K = 1024, BK = 64;
  __shared__ char smem[128 * 72 * 4];      // As(16K)+Bs(8K) / Ct[128][72] f32
  u16* As = (u16*)smem;
  u16* Bs = (u16*)(smem + 16384);
  float* Ct = (float*)smem;

  const int tid = threadIdx.x, lane = tid & 63, wave = tid >> 6;
  const int m0 = blockIdx.y * 128, n0 = blockIdx.x * 64;
  const int wr = (wave >> 1) * 64, wc = (wave & 1) * 32;
  const int fr = lane & 15, hk = lane >> 4;

  const int prow = tid >> 3;                 // 0..31
  const int sw8 = (tid & 7) ^ (prow & 7);
  const u16* ag = A  + (size_t)(m0 + prow) * K + sw8 * 8;
  const u16* bg = Bt + (size_t)(n0 + prow) * K + sw8 * 8;

  f32x4 acc[4][2] = {};

  for (int kt = 0; kt < K / BK; ++kt){
    #pragma unroll
    for (int r = 0; r < 4; ++r)
      gload_lds16(ag + (size_t)(r * 32) * K + kt * BK, (char*)As + r * 4096 + tid * 16);
    #pragma unroll
    for (int r = 0; r < 2; ++r)
      gload_lds16(bg + (size_t)(r * 32) * K + kt * BK, (char*)Bs + r * 4096 + tid * 16);
    __syncthreads();
    #pragma unroll
    for (int ks = 0; ks < 2; ++ks){
      bf16x8 af[4], bfr[2];
      #pragma unroll
      for (int mi = 0; mi < 4; ++mi){
        const int r = wr + mi * 16 + fr;
        const int cb = ((ks << 6) + (hk << 4)) ^ ((r & 7) << 4);
        af[mi] = *(const bf16x8*)((const char*)As + r * 128 + cb);
      }
      #pragma unroll
      for (int ni = 0; ni < 2; ++ni){
        const int r = wc + ni * 16 + fr;
        const int cb = ((ks << 6) + (hk << 4)) ^ ((r & 7) << 4);
        bfr[ni] = *(const bf16x8*)((const char*)Bs + r * 128 + cb);
      }
      #pragma unroll
      for (int mi = 0; mi < 4; ++mi)
        #pragma unroll
        for (int ni = 0; ni < 2; ++ni)
          acc[mi][ni] = __builtin_amdgcn_mfma_f32_16x16x32_bf16(af[mi], bfr[ni], acc[mi][ni], 0, 0, 0);
    }
    __syncthreads();
  }

  #pragma unroll
  for (int mi = 0; mi < 4; ++mi){
    const int r = wr + mi * 16 + (hk << 2);
    #pragma unroll
    for (int ni = 0; ni < 2; ++ni){
      const int c = wc + ni * 16 + fr;
      const float bs = bias[n0 + c];
      #pragma unroll
      for (int j = 0; j < 4; ++j)
        Ct[(r + j) * 72 + c] = acc[mi][ni][j] + bs;
    }
  }
  __syncthreads();
  #pragma unroll
  for (int it = 0; it < 8; ++it){
    const int flat = it * 256 + tid;
    const int row = flat >> 4, col4 = (flat & 15) * 4;
    float4 v = *(const float4*)(Ct + row * 72 + col4);
    *(float4*)(of + (size_t)(m0 + row) * EMB + n0 + col4) = v;
  }
}

// ---------------- sliding-window attention (R7 version: P written once bf16) -

__global__ __launch_bounds__(256) void attn_kernel(
    const u16* __restrict__ QKVb, const float* __restrict__ gate, u16* __restrict__ Ao)
{
  __shared__ float S[64 * 196];     // f32 scores; later re-used as bf16 P [64][200]
  __shared__ u16 KV[128 * 72];
  const int tid = threadIdx.x, lane = tid & 63, wave = tid >> 6;
  const int q0 = blockIdx.x * 64;
  const int bh = blockIdx.y;
  const u16* Qg = QKVb + (size_t)bh * HSZ;
  const u16* Kg = QKVb + (size_t)QKVSZ + (size_t)bh * HSZ;
  const u16* Vg = QKVb + (size_t)2 * QKVSZ + (size_t)bh * HSZ;
  const int kstart = q0 - WIN;
  u16* Pbf = (u16*)S;               // bf16 P, pitch 200 (25.6 KB < 50.2 KB)

  bf16x8 qf[4];
  {
    const u16* qp = Qg + (size_t)(q0 + wave * 16 + (lane & 15)) * HD + 8 * (lane >> 4);
    #pragma unroll
    for (int ks = 0; ks < 4; ++ks) qf[ks] = *(const bf16x8*)(qp + ks * 32);
  }
  const float scale = 0.08838834764831845f;

  for (int c = 0; c < 3; ++c){
    if (kstart + c * 64 + 64 <= 0){       // chunk entirely before t=0
      for (int t2 = tid; t2 < 64 * 64; t2 += 256)
        S[(t2 >> 6) * 196 + c * 64 + (t2 & 63)] = -1e30f;
      continue;
    }
    {
      const int keyl = tid >> 2;
      int krow = kstart + c * 64 + keyl;
      krow = min(max(krow, 0), SEQ - 1);
      const u16* kp = Kg + (size_t)krow * HD + (tid & 3) * 8;
      u16* ksh = &KV[keyl * 136 + (tid & 3) * 8];
      #pragma unroll
      for (int r = 0; r < 4; ++r)
        *(uint4*)(ksh + r * 32) = *(const uint4*)(kp + r * 32);
    }
    __syncthreads();
    f32x4 sacc[4] = {};
    #pragma unroll
    for (int ks = 0; ks < 4; ++ks){
      #pragma unroll
      for (int nf = 0; nf < 4; ++nf){
        bf16x8 kf = *(const bf16x8*)(&KV[(nf * 16 + (lane & 15)) * 136 + ks * 32 + 8 * (lane >> 4)]);
        sacc[nf] = __builtin_amdgcn_mfma_f32_16x16x32_bf16(qf[ks], kf, sacc[nf], 0, 0, 0);
      }
    }
    #pragma unroll
    for (int nf = 0; nf < 4; ++nf){
      const int kc = c * 64 + nf * 16 + (lane & 15);
      const int kg = kstart + kc;
      #pragma unroll
      for (int j = 0; j < 4; ++j){
        const int qr = wave * 16 + ((lane >> 4) << 2) + j;
        const int qg = q0 + qr;
        const bool ok = (kg >= 0) && (kg <= qg) && (qg - kg <= WIN);
        S[qr * 196 + kc] = ok ? sacc[nf][j] * scale : -1e30f;
      }
    }
    __syncthreads();
  }

  { // softmax: 4 lanes per row; normalize in regs, write bf16 P once
    const int r = tid >> 2, sub = tid & 3;
    float4 v[12];
    float mx = -1e30f;
    #pragma unroll
    for (int i = 0; i < 12; ++i){
      v[i] = *(const float4*)(&S[r * 196 + (sub + 4 * i) * 4]);
      mx = fmaxf(mx, fmaxf(fmaxf(v[i].x, v[i].y), fmaxf(v[i].z, v[i].w)));
    }
    mx = fmaxf(mx, __shfl_xor(mx, 1));
    mx = fmaxf(mx, __shfl_xor(mx, 2));
    float sum = 0.f;
    #pragma unroll
    for (int i = 0; i < 12; ++i){
      v[i].x = __expf(v[i].x - mx); v[i].y = __expf(v[i].y - mx);
      v[i].z = __expf(v[i].z - mx); v[i].w = __expf(v[i].w - mx);
      sum += v[i].x + v[i].y + v[i].z + v[i].w;
    }
    sum += __shfl_xor(sum, 1);
    sum += __shfl_xor(sum, 2);
    const float inv = 1.0f / sum;
    __syncthreads();               // ALL f32 S reads complete before bf16 overwrite
    #pragma unroll
    for (int i = 0; i < 12; ++i){
      uint2 w;
      w.x = (u32)f2bf(v[i].x * inv) | ((u32)f2bf(v[i].y * inv) << 16);
      w.y = (u32)f2bf(v[i].z * inv) | ((u32)f2bf(v[i].w * inv) << 16);
      *(uint2*)(Pbf + r * 200 + (sub + 4 * i) * 4) = w;
    }
  }
  __syncthreads();   // P visible to all waves

  f32x4 oacc[8] = {};
  for (int c = 0; c < 3; ++c){
    if (kstart + c * 64 + 64 <= 0) continue;
    {
      const int keyl = tid & 63;
      int krow = kstart + c * 64 + keyl;
      krow = min(max(krow, 0), SEQ - 1);
      const u16* vp = Vg + (size_t)krow * HD + (tid >> 6) * 32;
      #pragma unroll
      for (int r2 = 0; r2 < 4; ++r2){
        u16x8 vv = *(const u16x8*)(vp + r2 * 8);
        const int dbase = (tid >> 6) * 32 + r2 * 8;
        #pragma unroll
        for (int j = 0; j < 8; ++j)
          KV[(dbase + j) * 72 + keyl] = vv[j];
      }
    }
    __syncthreads();
    #pragma unroll
    for (int ks = 0; ks < 2; ++ks){
      bf16x8 pf = *(const bf16x8*)(Pbf + (wave * 16 + (lane & 15)) * 200
                                        + c * 64 + ks * 32 + 8 * (lane >> 4));
      #pragma unroll
      for (int nf = 0; nf < 8; ++nf){
        bf16x8 vf = *(const bf16x8*)(&KV[(nf * 16 + (lane & 15)) * 72 + ks * 32 + 8 * (lane >> 4)]);
        oacc[nf] = __builtin_amdgcn_mfma_f32_16x16x32_bf16(pf, vf, oacc[nf], 0, 0, 0);
      }
    }
    __syncthreads();
  }

  // epilogue: oacc*gate -> LDS bf16 [64][132-pitch] (reuse S), then u16x8 stores
  {
    u16* T2 = (u16*)S;
    const int b = bh >> 3, h = bh & 7;
    const int fr_ = lane & 15, hk_ = lane >> 4;
    #pragma unroll
    for (int nf = 0; nf < 8; ++nf){
      const int d = nf * 16 + fr_;
      const float gv = gate[h * HD + d];
      #pragma unroll
      for (int j = 0; j < 4; ++j){
        const int qr = wave * 16 + (hk_ << 2) + j;
        T2[qr * 132 + d] = f2bf(oacc[nf][j] * gv);
      }
    }
    __syncthreads();
    #pragma unroll
    for (int it = 0; it < 4; ++it){
      const int flat = it * 256 + tid;
      const int row = flat >> 4, col8 = (flat & 15) * 8;
      u16x8 v = *(const u16x8*)(T2 + row * 132 + col8);
      *(u16x8*)(Ao + ((size_t)(b * SEQ + q0 + row)) * EMB + h * HD + col8) = v;
    }
  }
}

// ---------------- launch ----------------

extern "C" void kernel_launch(void* const* d_in, const int* in_sizes, int n_in,
                              void* d_out, int out_size, void* d_ws, size_t ws_size,
                              hipStream_t stream)
{
  const float* x     = (const float*)d_in[0];
  const float* Wqkv  = (const float*)d_in[1];
  const float* bqkv  = (const float*)d_in[2];
  const float* Wproj = (const float*)d_in[3];
  const float* bproj = (const float*)d_in[4];
  const float* gate  = (const float*)d_in[5];
  float* out = (float*)d_out;

  u16* Xb   = (u16*)d_ws;                        // [4096][1024]
  u16* Wqt  = Xb   + (size_t)MTOT * EMB;         // [3072][1024]
  u16* Wpt  = Wqt  + (size_t)NQKV * EMB;         // [1024][1024]
  u16* QKVb = Wpt  + (size_t)EMB * EMB;          // q,k,v: [B,H,T,D]
  u16* Ao   = QKVb + (size_t)3 * QKVSZ;          // [4096][1024] gated attn out

  prep<<<dim3(6144), dim3(256), 0, stream>>>(x, Wqkv, Wproj, Xb, Wqt, Wpt);

  gemm_qkv<<<dim3(NQKV / 128, MTOT / 128), dim3(256), 0, stream>>>(Xb, Wqt, bqkv, QKVb);

  attn_kernel<<<dim3(SEQ / 64, NB * NH), dim3(256), 0, stream>>>(QKVb, gate, Ao);

  gemm_proj<<<dim3(EMB / 64, MTOT / 128), dim3(256), 0, stream>>>(Ao, Wpt, bproj, out);
}